// Round 3
// baseline (308.968 us; speedup 1.0000x reference)
//
#include <hip/hip_runtime.h>
#include <hip/hip_bf16.h>
#include <hip/hip_cooperative_groups.h>
#include <math.h>

namespace cg = cooperative_groups;

#define NROWS 8192
#define DIM 64
#define NTILE 64          // 8192 / 128 tiles per side
#define NPAIRS 2080       // NTILE*(NTILE+1)/2 upper-triangular tile pairs
#define NJOBS (2 * NPAIRS)  // 4160: user + pos grams

typedef __bf16 bf16x8 __attribute__((ext_vector_type(8)));
typedef float f32x4 __attribute__((ext_vector_type(4)));

// ws layout (every slot rewritten each launch; no atomics anywhere):
//   @0       part_align float[8192 max]   (one per gather wave)
//   @32768   part_gram  float[4*NJOBS]    (one per gram wave-job)
//   @131072  Xu bf16[8192*64]  (1 MB)
//   @131072+1MB  Xp bf16[8192*64]  (1 MB)

// ---- phase helpers ---------------------------------------------------------

__device__ __forceinline__ float gather_row(
    int row, int lane,
    const int* __restrict__ uid, const int* __restrict__ pid,
    const float* __restrict__ ut, const float* __restrict__ it,
    __hip_bfloat16* __restrict__ Xu, __hip_bfloat16* __restrict__ Xp)
{
    const float u = ut[(long)uid[row] * DIM + lane];
    const float p = it[(long)pid[row] * DIM + lane];
    float su = u * u, sp = p * p;
    #pragma unroll
    for (int m = 32; m >= 1; m >>= 1) {
        su += __shfl_xor(su, m, 64);
        sp += __shfl_xor(sp, m, 64);
    }
    const float un = u * rsqrtf(su);
    const float pn = p * rsqrtf(sp);
    Xu[row * DIM + lane] = __float2bfloat16(un);
    Xp[row * DIM + lane] = __float2bfloat16(pn);
    const float d = un - pn;
    float dd = d * d;
    #pragma unroll
    for (int m = 32; m >= 1; m >>= 1) dd += __shfl_xor(dd, m, 64);
    return dd;   // all lanes hold the row's squared distance
}

// One 128x128 upper-triangular tile job (t4 in [0, NJOBS)). Per-wave partial
// sum written to part_gram[t4*4 + wave] — no LDS, no atomics, no barriers.
__device__ __forceinline__ void gram_job(
    int t4, int tid,
    const __hip_bfloat16* __restrict__ Xu, const __hip_bfloat16* __restrict__ Xp,
    float* __restrict__ part_gram)
{
    const int z = (t4 >= NPAIRS) ? 1 : 0;
    const int t = t4 - z * NPAIRS;
    const __hip_bfloat16* __restrict__ X = z ? Xp : Xu;

    // decode lower-tri pair (i >= j): t = i*(i+1)/2 + j
    int i = (int)((sqrtf(8.0f * (float)t + 1.0f) - 1.0f) * 0.5f);
    while (i * (i + 1) / 2 > t) --i;
    while ((i + 1) * (i + 2) / 2 <= t) ++i;
    const int j = t - i * (i + 1) / 2;
    const int bi = j, bj = i;           // bi <= bj

    const int lane = tid & 63;
    const int w    = tid >> 6;          // 0..3
    const int wr   = w >> 1, wc = w & 1;
    const int r    = lane & 15;         // row within 16-tile
    const int koff = (lane >> 4) * 8;   // quad*8: 8 consecutive bf16 k-values

    const int i_base = bi * 128 + wr * 64;
    const int j_base = bj * 128 + wc * 64;

    bf16x8 a[4][2], b[4][2];
    #pragma unroll
    for (int tt = 0; tt < 4; ++tt) {
        const __hip_bfloat16* pa = X + (i_base + tt * 16 + r) * DIM + koff;
        a[tt][0] = *reinterpret_cast<const bf16x8*>(pa);
        a[tt][1] = *reinterpret_cast<const bf16x8*>(pa + 32);
        const __hip_bfloat16* pb = X + (j_base + tt * 16 + r) * DIM + koff;
        b[tt][0] = *reinterpret_cast<const bf16x8*>(pb);
        b[tt][1] = *reinterpret_cast<const bf16x8*>(pb + 32);
    }

    f32x4 acc[4][4];
    #pragma unroll
    for (int mt = 0; mt < 4; ++mt)
        #pragma unroll
        for (int nt = 0; nt < 4; ++nt) {
            f32x4 c = {0.f, 0.f, 0.f, 0.f};
            c = __builtin_amdgcn_mfma_f32_16x16x32_bf16(a[mt][0], b[nt][0], c, 0, 0, 0);
            c = __builtin_amdgcn_mfma_f32_16x16x32_bf16(a[mt][1], b[nt][1], c, 0, 0, 0);
            acc[mt][nt] = c;
        }

    // e = exp(4*sim - 4) = exp2(C4*sim - C4); tile sum is lane-layout-invariant.
    const float C4 = 5.770780163555851f;  // 4 * log2(e)
    float s0 = 0.f, s1 = 0.f, s2 = 0.f, s3 = 0.f;
    #pragma unroll
    for (int mt = 0; mt < 4; ++mt)
        #pragma unroll
        for (int nt = 0; nt < 4; ++nt) {
            s0 += __builtin_amdgcn_exp2f(fmaf(C4, acc[mt][nt][0], -C4));
            s1 += __builtin_amdgcn_exp2f(fmaf(C4, acc[mt][nt][1], -C4));
            s2 += __builtin_amdgcn_exp2f(fmaf(C4, acc[mt][nt][2], -C4));
            s3 += __builtin_amdgcn_exp2f(fmaf(C4, acc[mt][nt][3], -C4));
        }
    float s = (s0 + s1) + (s2 + s3);
    #pragma unroll
    for (int m = 32; m >= 1; m >>= 1) s += __shfl_xor(s, m, 64);

    if (lane == 0)
        part_gram[t4 * 4 + w] = ((bi == bj) ? 1.f : 2.f) * s;
}

__device__ __forceinline__ void finalize_block(
    const float* __restrict__ pa, const float* __restrict__ pg,
    float* __restrict__ out, int tid, int na)
{
    float a = 0.f, su = 0.f, sp = 0.f;
    for (int k = tid; k < na; k += 256)          a  += pa[k];
    for (int k = tid; k < 4 * NPAIRS; k += 256)  su += pg[k];
    for (int k = tid; k < 4 * NPAIRS; k += 256)  sp += pg[4 * NPAIRS + k];
    #pragma unroll
    for (int m = 32; m >= 1; m >>= 1) {
        a  += __shfl_xor(a, m, 64);
        su += __shfl_xor(su, m, 64);
        sp += __shfl_xor(sp, m, 64);
    }
    __shared__ float ra[4], ru[4], rp[4];
    const int w = tid >> 6, lane = tid & 63;
    if (lane == 0) { ra[w] = a; ru[w] = su; rp[w] = sp; }
    __syncthreads();
    if (tid == 0) {
        const float A  = ra[0] + ra[1] + ra[2] + ra[3];
        const float SU = ru[0] + ru[1] + ru[2] + ru[3];
        const float SP = rp[0] + rp[1] + rp[2] + rp[3];
        const float n = 8192.f;
        const float npairs = 8192.f * 8191.f * 0.5f;
        out[0] = A / n + 0.5f * (logf((SU - n) * 0.5f / npairs)
                               + logf((SP - n) * 0.5f / npairs));  // GAMMA=1
    }
}

// ---- fused cooperative kernel ---------------------------------------------

__global__ __launch_bounds__(256) void fused_kernel(
    const int* __restrict__ uid, const int* __restrict__ pid,
    const float* __restrict__ ut, const float* __restrict__ it,
    float* __restrict__ part_align, float* __restrict__ part_gram,
    __hip_bfloat16* __restrict__ Xu, __hip_bfloat16* __restrict__ Xp,
    float* __restrict__ out)
{
    const int tid  = threadIdx.x;
    const int lane = tid & 63;
    const int w    = tid >> 6;
    const int wave_gid  = blockIdx.x * 4 + w;
    const int num_waves = gridDim.x * 4;

    // phase 1: gather + normalize + alignment partials (grid-stride over rows)
    float dd = 0.f;
    for (int row = wave_gid; row < NROWS; row += num_waves)
        dd += gather_row(row, lane, uid, pid, ut, it, Xu, Xp);
    if (lane == 0) part_align[wave_gid] = dd;

    __threadfence();
    cg::this_grid().sync();

    // phase 2: gram tiles (grid-stride over jobs)
    for (int t4 = blockIdx.x; t4 < NJOBS; t4 += gridDim.x)
        gram_job(t4, tid, Xu, Xp, part_gram);

    __threadfence();
    cg::this_grid().sync();

    // phase 3: final reduction + scalar math
    if (blockIdx.x == 0)
        finalize_block(part_align, part_gram, out, tid, num_waves);
}

// ---- non-cooperative fallback ---------------------------------------------

__global__ __launch_bounds__(256) void k_gather(
    const int* __restrict__ uid, const int* __restrict__ pid,
    const float* __restrict__ ut, const float* __restrict__ it,
    float* __restrict__ part_align,
    __hip_bfloat16* __restrict__ Xu, __hip_bfloat16* __restrict__ Xp)
{
    const int lane = threadIdx.x & 63, w = threadIdx.x >> 6;
    const int row = blockIdx.x * 4 + w;                 // grid 2048 -> 8192 rows
    const float dd = gather_row(row, lane, uid, pid, ut, it, Xu, Xp);
    if (lane == 0) part_align[row] = dd;
}

__global__ __launch_bounds__(256) void k_gram(
    const __hip_bfloat16* __restrict__ Xu, const __hip_bfloat16* __restrict__ Xp,
    float* __restrict__ part_gram)
{
    gram_job(blockIdx.x, threadIdx.x, Xu, Xp, part_gram);
}

__global__ __launch_bounds__(256) void k_final(
    const float* __restrict__ pa, const float* __restrict__ pg,
    float* __restrict__ out)
{
    finalize_block(pa, pg, out, threadIdx.x, NROWS);
}

// ---- launcher --------------------------------------------------------------

extern "C" void kernel_launch(void* const* d_in, const int* in_sizes, int n_in,
                              void* d_out, int out_size, void* d_ws, size_t ws_size,
                              hipStream_t stream)
{
    const int*   uid = (const int*)d_in[0];
    const int*   pid = (const int*)d_in[1];
    // d_in[2] = neg_id (unused by the reference output)
    const float* ut  = (const float*)d_in[3];
    const float* it  = (const float*)d_in[4];
    float* out = (float*)d_out;

    float* part_align = (float*)d_ws;                          // up to 8192 floats
    float* part_gram  = (float*)((char*)d_ws + 32768);         // 4*NJOBS floats
    __hip_bfloat16* Xu = (__hip_bfloat16*)((char*)d_ws + 131072);
    __hip_bfloat16* Xp = Xu + (size_t)NROWS * DIM;

    // Cooperative grid sized for guaranteed co-residency (256 CUs).
    int nb = 0;
    hipError_t qe = hipOccupancyMaxActiveBlocksPerMultiprocessor(
        &nb, (const void*)fused_kernel, 256, 0);
    int grid = (qe == hipSuccess && nb > 0) ? nb * 256 : 0;
    if (grid > 2048) grid = 2048;

    hipError_t err = hipErrorUnknown;
    if (grid > 0) {
        void* args[] = {(void*)&uid, (void*)&pid, (void*)&ut, (void*)&it,
                        (void*)&part_align, (void*)&part_gram,
                        (void*)&Xu, (void*)&Xp, (void*)&out};
        err = hipLaunchCooperativeKernel((const void*)fused_kernel,
                                         dim3(grid), dim3(256), args, 0, stream);
    }
    if (err != hipSuccess) {
        (void)hipGetLastError();   // clear, fall back to 3-kernel path
        k_gather<<<NROWS / 4, 256, 0, stream>>>(uid, pid, ut, it, part_align, Xu, Xp);
        k_gram<<<NJOBS, 256, 0, stream>>>(Xu, Xp, part_gram);
        k_final<<<1, 256, 0, stream>>>(part_align, part_gram, out);
    }
}

// Round 4
// 148.522 us; speedup vs baseline: 2.0803x; 2.0803x over previous
//
#include <hip/hip_runtime.h>
#include <hip/hip_bf16.h>
#include <math.h>

#define NROWS 8192
#define DIM 64
#define NTILE 64          // 8192 / 128 tiles per side
#define NPAIRS 2080       // NTILE*(NTILE+1)/2 upper-triangular tile pairs
#define NJOBS (2 * NPAIRS)  // 4160: user + pos grams

typedef __bf16 bf16x8 __attribute__((ext_vector_type(8)));
typedef float f32x4 __attribute__((ext_vector_type(4)));

// ws layout (every slot rewritten each launch; no atomics anywhere):
//   @0       part_align float[8192]      (one per gather row)
//   @32768   part_gram  float[4*NJOBS]   (one per gram wave-job)
//   @131072  Xu bf16[8192*64]  (1 MB)
//   @131072+1MB  Xp bf16[8192*64]  (1 MB)

__device__ __forceinline__ float gather_row(
    int row, int lane,
    const int* __restrict__ uid, const int* __restrict__ pid,
    const float* __restrict__ ut, const float* __restrict__ it,
    __hip_bfloat16* __restrict__ Xu, __hip_bfloat16* __restrict__ Xp)
{
    const float u = ut[(long)uid[row] * DIM + lane];
    const float p = it[(long)pid[row] * DIM + lane];
    float su = u * u, sp = p * p;
    #pragma unroll
    for (int m = 32; m >= 1; m >>= 1) {
        su += __shfl_xor(su, m, 64);
        sp += __shfl_xor(sp, m, 64);
    }
    const float un = u * rsqrtf(su);
    const float pn = p * rsqrtf(sp);
    Xu[row * DIM + lane] = __float2bfloat16(un);
    Xp[row * DIM + lane] = __float2bfloat16(pn);
    const float d = un - pn;
    float dd = d * d;
    #pragma unroll
    for (int m = 32; m >= 1; m >>= 1) dd += __shfl_xor(dd, m, 64);
    return dd;   // all lanes hold the row's squared distance
}

// One 128x128 upper-triangular tile job (t4 in [0, NJOBS)). Per-wave partial
// sum written to part_gram[t4*4 + wave] — no LDS reduction, no atomics.
__device__ __forceinline__ void gram_job(
    int t4, int tid,
    const __hip_bfloat16* __restrict__ Xu, const __hip_bfloat16* __restrict__ Xp,
    float* __restrict__ part_gram)
{
    const int z = (t4 >= NPAIRS) ? 1 : 0;
    const int t = t4 - z * NPAIRS;
    const __hip_bfloat16* __restrict__ X = z ? Xp : Xu;

    // decode lower-tri pair (i >= j): t = i*(i+1)/2 + j
    int i = (int)((sqrtf(8.0f * (float)t + 1.0f) - 1.0f) * 0.5f);
    while (i * (i + 1) / 2 > t) --i;
    while ((i + 1) * (i + 2) / 2 <= t) ++i;
    const int j = t - i * (i + 1) / 2;
    const int bi = j, bj = i;           // bi <= bj

    const int lane = tid & 63;
    const int w    = tid >> 6;          // 0..3
    const int wr   = w >> 1, wc = w & 1;
    const int r    = lane & 15;         // row within 16-tile
    const int koff = (lane >> 4) * 8;   // quad*8: 8 consecutive bf16 k-values

    const int i_base = bi * 128 + wr * 64;
    const int j_base = bj * 128 + wc * 64;

    bf16x8 a[4][2], b[4][2];
    #pragma unroll
    for (int tt = 0; tt < 4; ++tt) {
        const __hip_bfloat16* pa = X + (i_base + tt * 16 + r) * DIM + koff;
        a[tt][0] = *reinterpret_cast<const bf16x8*>(pa);
        a[tt][1] = *reinterpret_cast<const bf16x8*>(pa + 32);
        const __hip_bfloat16* pb = X + (j_base + tt * 16 + r) * DIM + koff;
        b[tt][0] = *reinterpret_cast<const bf16x8*>(pb);
        b[tt][1] = *reinterpret_cast<const bf16x8*>(pb + 32);
    }

    f32x4 acc[4][4];
    #pragma unroll
    for (int mt = 0; mt < 4; ++mt)
        #pragma unroll
        for (int nt = 0; nt < 4; ++nt) {
            f32x4 c = {0.f, 0.f, 0.f, 0.f};
            c = __builtin_amdgcn_mfma_f32_16x16x32_bf16(a[mt][0], b[nt][0], c, 0, 0, 0);
            c = __builtin_amdgcn_mfma_f32_16x16x32_bf16(a[mt][1], b[nt][1], c, 0, 0, 0);
            acc[mt][nt] = c;
        }

    // e = exp(4*sim - 4) = exp2(C4*sim - C4); tile sum is lane-layout-invariant.
    const float C4 = 5.770780163555851f;  // 4 * log2(e)
    float s0 = 0.f, s1 = 0.f, s2 = 0.f, s3 = 0.f;
    #pragma unroll
    for (int mt = 0; mt < 4; ++mt)
        #pragma unroll
        for (int nt = 0; nt < 4; ++nt) {
            s0 += __builtin_amdgcn_exp2f(fmaf(C4, acc[mt][nt][0], -C4));
            s1 += __builtin_amdgcn_exp2f(fmaf(C4, acc[mt][nt][1], -C4));
            s2 += __builtin_amdgcn_exp2f(fmaf(C4, acc[mt][nt][2], -C4));
            s3 += __builtin_amdgcn_exp2f(fmaf(C4, acc[mt][nt][3], -C4));
        }
    float s = (s0 + s1) + (s2 + s3);
    #pragma unroll
    for (int m = 32; m >= 1; m >>= 1) s += __shfl_xor(s, m, 64);

    if (lane == 0)
        part_gram[t4 * 4 + w] = ((bi == bj) ? 1.f : 2.f) * s;
}

__global__ __launch_bounds__(256) void k_gather(
    const int* __restrict__ uid, const int* __restrict__ pid,
    const float* __restrict__ ut, const float* __restrict__ it,
    float* __restrict__ part_align,
    __hip_bfloat16* __restrict__ Xu, __hip_bfloat16* __restrict__ Xp)
{
    const int lane = threadIdx.x & 63, w = threadIdx.x >> 6;
    const int row = blockIdx.x * 4 + w;                 // grid 2048 -> 8192 rows
    const float dd = gather_row(row, lane, uid, pid, ut, it, Xu, Xp);
    if (lane == 0) part_align[row] = dd;
}

__global__ __launch_bounds__(256) void k_gram(
    const __hip_bfloat16* __restrict__ Xu, const __hip_bfloat16* __restrict__ Xp,
    float* __restrict__ part_gram)
{
    gram_job(blockIdx.x, threadIdx.x, Xu, Xp, part_gram);
}

__global__ __launch_bounds__(256) void k_final(
    const float* __restrict__ pa, const float* __restrict__ pg,
    float* __restrict__ out)
{
    const int tid = threadIdx.x;
    float a = 0.f, su = 0.f, sp = 0.f;
    for (int k = tid; k < NROWS; k += 256)       a  += pa[k];
    for (int k = tid; k < 4 * NPAIRS; k += 256)  su += pg[k];
    for (int k = tid; k < 4 * NPAIRS; k += 256)  sp += pg[4 * NPAIRS + k];
    #pragma unroll
    for (int m = 32; m >= 1; m >>= 1) {
        a  += __shfl_xor(a, m, 64);
        su += __shfl_xor(su, m, 64);
        sp += __shfl_xor(sp, m, 64);
    }
    __shared__ float ra[4], ru[4], rp[4];
    const int w = tid >> 6, lane = tid & 63;
    if (lane == 0) { ra[w] = a; ru[w] = su; rp[w] = sp; }
    __syncthreads();
    if (tid == 0) {
        const float A  = ra[0] + ra[1] + ra[2] + ra[3];
        const float SU = ru[0] + ru[1] + ru[2] + ru[3];
        const float SP = rp[0] + rp[1] + rp[2] + rp[3];
        const float n = 8192.f;
        const float npairs = 8192.f * 8191.f * 0.5f;
        out[0] = A / n + 0.5f * (logf((SU - n) * 0.5f / npairs)
                               + logf((SP - n) * 0.5f / npairs));  // GAMMA=1
    }
}

extern "C" void kernel_launch(void* const* d_in, const int* in_sizes, int n_in,
                              void* d_out, int out_size, void* d_ws, size_t ws_size,
                              hipStream_t stream)
{
    const int*   uid = (const int*)d_in[0];
    const int*   pid = (const int*)d_in[1];
    // d_in[2] = neg_id (unused by the reference output)
    const float* ut  = (const float*)d_in[3];
    const float* it  = (const float*)d_in[4];
    float* out = (float*)d_out;

    float* part_align = (float*)d_ws;                          // 8192 floats
    float* part_gram  = (float*)((char*)d_ws + 32768);         // 4*NJOBS floats
    __hip_bfloat16* Xu = (__hip_bfloat16*)((char*)d_ws + 131072);
    __hip_bfloat16* Xp = Xu + (size_t)NROWS * DIM;

    k_gather<<<NROWS / 4, 256, 0, stream>>>(uid, pid, ut, it, part_align, Xu, Xp);
    k_gram<<<NJOBS, 256, 0, stream>>>(Xu, Xp, part_gram);
    k_final<<<1, 256, 0, stream>>>(part_align, part_gram, out);
}